// Round 3
// baseline (490.225 us; speedup 1.0000x reference)
//
#include <hip/hip_runtime.h>

#define NB 16
#define DMODEL 384
#define SDIM 64
#define LSEQ 4096
#define C3S 192

// ---------------- k1: raw[b,o,l] = sum_d W_bcdt[o,d] * x[b,d,l] ----------------
// grid (4 ltiles, 24 ogroups, 16 b), block 256. 8 o x 4 l per thread.
__global__ __launch_bounds__(256) void k1_bcdt(const float* __restrict__ x,
                                               const float* __restrict__ Wb,
                                               float* __restrict__ raw) {
    __shared__ float WT[DMODEL][8];
    const int t = threadIdx.x;
    const int ltile = blockIdx.x;
    const int og = blockIdx.y;
    const int b = blockIdx.z;
    const int obase = og * 8;
    #pragma unroll
    for (int i = 0; i < 12; ++i) {
        int idx = t + i * 256;          // 0..3071 over 8x384
        int oo = idx / 384, d = idx % 384;
        WT[d][oo] = Wb[(obase + oo) * DMODEL + d];
    }
    __syncthreads();
    const int l0 = ltile * 1024 + t * 4;
    const float* xp = x + (size_t)b * DMODEL * LSEQ + l0;
    float acc[8][4];
    #pragma unroll
    for (int k = 0; k < 8; ++k)
        #pragma unroll
        for (int j = 0; j < 4; ++j) acc[k][j] = 0.f;

    #pragma unroll 2
    for (int d = 0; d < DMODEL; ++d) {
        float4 xv = *reinterpret_cast<const float4*>(xp + (size_t)d * LSEQ);
        float4 w0 = *reinterpret_cast<const float4*>(&WT[d][0]);
        float4 w1 = *reinterpret_cast<const float4*>(&WT[d][4]);
        float w[8] = {w0.x, w0.y, w0.z, w0.w, w1.x, w1.y, w1.z, w1.w};
        #pragma unroll
        for (int k = 0; k < 8; ++k) {
            acc[k][0] = fmaf(w[k], xv.x, acc[k][0]);
            acc[k][1] = fmaf(w[k], xv.y, acc[k][1]);
            acc[k][2] = fmaf(w[k], xv.z, acc[k][2]);
            acc[k][3] = fmaf(w[k], xv.w, acc[k][3]);
        }
    }
    float* op = raw + ((size_t)b * C3S + obase) * LSEQ + l0;
    #pragma unroll
    for (int k = 0; k < 8; ++k) {
        *reinterpret_cast<float4*>(op + (size_t)k * LSEQ) =
            make_float4(acc[k][0], acc[k][1], acc[k][2], acc[k][3]);
    }
}

// ---------------- k2c: Cm[b,s,l] = dwconv3x3(raw[b,64+s,:,:]) ----------------
// grid (16 rowgroups, 64 s, 16 b), block 256 = 4 rows x 64 cols
__global__ __launch_bounds__(256) void k2c_cm(const float* __restrict__ raw,
                                              const float* __restrict__ Wdw,
                                              float* __restrict__ Cm) {
    const int t = threadIdx.x;
    const int rg = blockIdx.x;
    const int c = blockIdx.y;
    const int b = blockIdx.z;
    const int row = rg * 4 + (t >> 6);
    const int col = t & 63;
    float w[9];
    #pragma unroll
    for (int k = 0; k < 9; ++k) w[k] = Wdw[(64 + c) * 9 + k];
    const float* ip = raw + ((size_t)b * C3S + 64 + c) * LSEQ;
    float acc = 0.f;
    #pragma unroll
    for (int dy = -1; dy <= 1; ++dy) {
        int r = row + dy;
        if (r < 0 || r > 63) continue;
        #pragma unroll
        for (int dx = -1; dx <= 1; ++dx) {
            int cc = col + dx;
            if (cc < 0 || cc > 63) continue;
            acc = fmaf(w[(dy + 1) * 3 + (dx + 1)], ip[r * 64 + cc], acc);
        }
    }
    Cm[((size_t)b * SDIM + c) * LSEQ + row * 64 + col] = acc;
}

// ---------------- k23: fused dwconv(B,dt) + softmax + AB = A*Bconv ----------------
// grid (64 s, 16 b), block 256, 16 pixels/thread; both channels staged in LDS
__global__ __launch_bounds__(256) void k23_ab(const float* __restrict__ raw,
                                              const float* __restrict__ Wdw,
                                              const float* __restrict__ Ap,
                                              float* __restrict__ AB) {
    __shared__ float chB[LSEQ];
    __shared__ float chT[LSEQ];
    __shared__ float red[4];
    const int t = threadIdx.x;
    const int s = blockIdx.x;
    const int b = blockIdx.y;
    const float* rB = raw + ((size_t)b * C3S + s) * LSEQ;
    const float* rT = raw + ((size_t)b * C3S + 128 + s) * LSEQ;
    #pragma unroll
    for (int i = 0; i < 16; ++i) {
        int idx = t + i * 256;
        chB[idx] = rB[idx];
        chT[idx] = rT[idx];
    }
    __syncthreads();
    float wB[9], wT[9];
    #pragma unroll
    for (int k = 0; k < 9; ++k) {
        wB[k] = Wdw[s * 9 + k];
        wT[k] = Wdw[(128 + s) * 9 + k];
    }
    const float a = Ap[s];
    float vB[16], vT[16];
    float m = -3.0e38f;
    #pragma unroll
    for (int i = 0; i < 16; ++i) {
        int idx = t + i * 256;
        int row = idx >> 6, col = idx & 63;
        float aB = 0.f, aT = 0.f;
        #pragma unroll
        for (int dy = -1; dy <= 1; ++dy) {
            int r = row + dy;
            if (r < 0 || r > 63) continue;
            #pragma unroll
            for (int dx = -1; dx <= 1; ++dx) {
                int cc = col + dx;
                if (cc < 0 || cc > 63) continue;
                int p = r * 64 + cc;
                int wi = (dy + 1) * 3 + (dx + 1);
                aB = fmaf(wB[wi], chB[p], aB);
                aT = fmaf(wT[wi], chT[p], aT);
            }
        }
        vB[i] = aB;
        vT[i] = aT + a;
        m = fmaxf(m, vT[i]);
    }
    #pragma unroll
    for (int off = 32; off; off >>= 1) m = fmaxf(m, __shfl_xor(m, off));
    if ((t & 63) == 0) red[t >> 6] = m;
    __syncthreads();
    m = fmaxf(fmaxf(red[0], red[1]), fmaxf(red[2], red[3]));
    __syncthreads();
    float sum = 0.f;
    #pragma unroll
    for (int i = 0; i < 16; ++i) {
        vT[i] = expf(vT[i] - m);
        sum += vT[i];
    }
    #pragma unroll
    for (int off = 32; off; off >>= 1) sum += __shfl_xor(sum, off);
    if ((t & 63) == 0) red[t >> 6] = sum;
    __syncthreads();
    sum = red[0] + red[1] + red[2] + red[3];
    const float inv = 1.0f / sum;
    float* op = AB + ((size_t)b * SDIM + s) * LSEQ;
    #pragma unroll
    for (int i = 0; i < 16; ++i) {
        int idx = t + i * 256;
        op[idx] = vT[i] * inv * vB[i];
    }
}

// ---------------- k4: h[b,d,s] = sum_l x[b,d,l] * AB[b,s,l] ----------------
// grid (24 dtiles of 16, 16 b), block 256, 2d x 2s per thread, LDS-tiled over l
__global__ __launch_bounds__(256) void k4_h(const float* __restrict__ x,
                                            const float* __restrict__ AB,
                                            float* __restrict__ h) {
    __shared__ float xsT[128][18];
    __shared__ float abT[128][66];
    const int t = threadIdx.x;
    const int dt = blockIdx.x;
    const int b = blockIdx.y;
    const int d0 = dt * 16;
    const int dq = t >> 5;    // 0..7
    const int sq = t & 31;    // 0..31
    float acc00 = 0.f, acc01 = 0.f, acc10 = 0.f, acc11 = 0.f;
    const float* xp = x + ((size_t)b * DMODEL + d0) * LSEQ;
    const float* ap = AB + (size_t)b * SDIM * LSEQ;
    for (int lc = 0; lc < LSEQ; lc += 128) {
        #pragma unroll
        for (int i = 0; i < 8; ++i) {
            int idx = t + i * 256; int dd = idx >> 7; int j = idx & 127;
            xsT[j][dd] = xp[(size_t)dd * LSEQ + lc + j];
        }
        #pragma unroll
        for (int i = 0; i < 32; ++i) {
            int idx = t + i * 256; int ss = idx >> 7; int j = idx & 127;
            abT[j][ss] = ap[(size_t)ss * LSEQ + lc + j];
        }
        __syncthreads();
        #pragma unroll 4
        for (int j = 0; j < 128; ++j) {
            float2 xv = *reinterpret_cast<const float2*>(&xsT[j][2 * dq]);
            float2 av = *reinterpret_cast<const float2*>(&abT[j][2 * sq]);
            acc00 = fmaf(xv.x, av.x, acc00);
            acc01 = fmaf(xv.x, av.y, acc01);
            acc10 = fmaf(xv.y, av.x, acc10);
            acc11 = fmaf(xv.y, av.y, acc11);
        }
        __syncthreads();
    }
    float* hp = h + ((size_t)b * DMODEL + d0 + 2 * dq) * SDIM + 2 * sq;
    hp[0] = acc00; hp[1] = acc01;
    hp[SDIM] = acc10; hp[SDIM + 1] = acc11;
}

// ---------------- k5a: hgate[b,o,s] = h1*silu(z) + h1*D ----------------
// grid (24 otiles of 16, 16 b), block 256 = 64 s x 4 ogroups, 4 o per thread
__global__ __launch_bounds__(256) void k5a(const float* __restrict__ h,
                                           const float* __restrict__ Whz,
                                           const float* __restrict__ Dp,
                                           float* __restrict__ hgate) {
    const int t = threadIdx.x;
    const int ot = blockIdx.x;
    const int b = blockIdx.y;
    const int s = t & 63;
    const int og = t >> 6;
    const int o0 = ot * 16 + og * 4;
    const float* hp = h + (size_t)b * DMODEL * SDIM + s;
    float acc1[4] = {0.f, 0.f, 0.f, 0.f};
    float acc2[4] = {0.f, 0.f, 0.f, 0.f};
    for (int d = 0; d < DMODEL; d += 2) {
        float h0 = hp[(size_t)d * SDIM];
        float h1 = hp[(size_t)(d + 1) * SDIM];
        #pragma unroll
        for (int k = 0; k < 4; ++k) {
            float2 w1 = *reinterpret_cast<const float2*>(&Whz[(o0 + k) * DMODEL + d]);
            float2 w2 = *reinterpret_cast<const float2*>(&Whz[(DMODEL + o0 + k) * DMODEL + d]);
            acc1[k] = fmaf(w1.x, h0, acc1[k]);
            acc1[k] = fmaf(w1.y, h1, acc1[k]);
            acc2[k] = fmaf(w2.x, h0, acc2[k]);
            acc2[k] = fmaf(w2.y, h1, acc2[k]);
        }
    }
    const float Dv = Dp[0];
    float* gp = hgate + ((size_t)b * DMODEL + o0) * SDIM + s;
    #pragma unroll
    for (int k = 0; k < 4; ++k) {
        float z = acc2[k];
        float sig = 1.f / (1.f + expf(-z));
        gp[(size_t)k * SDIM] = acc1[k] * (z * sig) + acc1[k] * Dv;
    }
}

// ---------------- k5b: hout[b,o,s] = sum_e W_out[o,e]*hgate[b,e,s] (to d_out tail) --
__global__ __launch_bounds__(256) void k5b(const float* __restrict__ hg,
                                           const float* __restrict__ Wout,
                                           float* __restrict__ ho) {
    const int t = threadIdx.x;
    const int ot = blockIdx.x;
    const int b = blockIdx.y;
    const int s = t & 63;
    const int og = t >> 6;
    const int o0 = ot * 16 + og * 4;
    const float* gp = hg + (size_t)b * DMODEL * SDIM + s;
    float acc[4] = {0.f, 0.f, 0.f, 0.f};
    for (int d = 0; d < DMODEL; d += 2) {
        float g0 = gp[(size_t)d * SDIM];
        float g1 = gp[(size_t)(d + 1) * SDIM];
        #pragma unroll
        for (int k = 0; k < 4; ++k) {
            float2 w = *reinterpret_cast<const float2*>(&Wout[(o0 + k) * DMODEL + d]);
            acc[k] = fmaf(w.x, g0, acc[k]);
            acc[k] = fmaf(w.y, g1, acc[k]);
        }
    }
    float* op = ho + ((size_t)b * DMODEL + o0) * SDIM + s;
    #pragma unroll
    for (int k = 0; k < 4; ++k) op[(size_t)k * SDIM] = acc[k];
}

// ---------------- k6: y[b,d,l] = sum_s hout[b,d,s] * Cm[b,s,l] ----------------
// grid (16 ltiles, 24 dtiles of 16, 16 b), block 256 (one l each), 16 d per thread
__global__ __launch_bounds__(256) void k6_y(const float* __restrict__ Cm,
                                            const float* __restrict__ ho,
                                            float* __restrict__ y) {
    __shared__ float hs[16 * 64];
    const int t = threadIdx.x;
    const int lt = blockIdx.x;
    const int dtile = blockIdx.y;
    const int b = blockIdx.z;
    const int l = lt * 256 + t;
    const int d0 = dtile * 16;
    #pragma unroll
    for (int i = 0; i < 4; ++i) {
        int idx = t + i * 256;          // 0..1023 over 16 d x 64 s
        int k = idx >> 6, s = idx & 63;
        hs[idx] = ho[((size_t)b * DMODEL + d0 + k) * SDIM + s];
    }
    __syncthreads();
    const float* cp = Cm + (size_t)b * SDIM * LSEQ + l;
    float acc[16];
    #pragma unroll
    for (int k = 0; k < 16; ++k) acc[k] = 0.f;
    for (int s = 0; s < SDIM; ++s) {
        float cv = cp[(size_t)s * LSEQ];
        #pragma unroll
        for (int k = 0; k < 16; ++k) acc[k] = fmaf(hs[k * 64 + s], cv, acc[k]);
    }
    float* yp = y + ((size_t)b * DMODEL + d0) * LSEQ + l;
    #pragma unroll
    for (int k = 0; k < 16; ++k) yp[(size_t)k * LSEQ] = acc[k];
}

extern "C" void kernel_launch(void* const* d_in, const int* in_sizes, int n_in,
                              void* d_out, int out_size, void* d_ws, size_t ws_size,
                              hipStream_t stream) {
    const float* x    = (const float*)d_in[0];
    const float* Wb   = (const float*)d_in[1];
    const float* Wdw  = (const float*)d_in[2];
    const float* Whz  = (const float*)d_in[3];
    const float* Wout = (const float*)d_in[4];
    const float* Ap   = (const float*)d_in[5];
    const float* Dp   = (const float*)d_in[6];

    float* out = (float*)d_out;
    const size_t YSIZE = (size_t)NB * DMODEL * LSEQ;   // 25165824 floats

    // Scratch carved out of d_out's y-region (dead until k6 rewrites it):
    //   raw [0,        12582912)  -- bcdt pre-conv (16*192*4096)
    //   AB  [12582912, 16777216)  -- 16*64*4096
    //   h   [16777216, 17170432)  -- 16*384*64
    //   hg  [17170432, 17563648)
    // Cm lives in d_ws (k6 reads it WHILE overwriting the y-region).
    float* raw = out;
    float* AB  = out + 12582912;
    float* h   = out + 16777216;
    float* hg  = out + 17170432;
    float* ho  = out + YSIZE;          // hout: real output region (f32)
    float* Cm  = (float*)d_ws;         // 4194304 floats = 16.8 MB

    k1_bcdt<<<dim3(4, 24, NB), 256, 0, stream>>>(x, Wb, raw);
    k2c_cm <<<dim3(16, SDIM, NB), 256, 0, stream>>>(raw, Wdw, Cm);
    k23_ab <<<dim3(SDIM, NB), 256, 0, stream>>>(raw, Wdw, Ap, AB);
    k4_h   <<<dim3(24, NB), 256, 0, stream>>>(x, AB, h);
    k5a    <<<dim3(24, NB), 256, 0, stream>>>(h, Whz, Dp, hg);
    k5b    <<<dim3(24, NB), 256, 0, stream>>>(hg, Wout, ho);
    k6_y   <<<dim3(16, 24, NB), 256, 0, stream>>>(Cm, ho, out);
}

// Round 5
// 275.242 us; speedup vs baseline: 1.7811x; 1.7811x over previous
//
#include <hip/hip_runtime.h>

typedef unsigned short u16;
typedef short s16x8 __attribute__((ext_vector_type(8)));
typedef float f32x4 __attribute__((ext_vector_type(4)));

#define NB 16
#define DMODEL 384
#define SDIM 64
#define LSEQ 4096
#define C3S 192

__device__ __forceinline__ float b2f(u16 u) {
    union { unsigned int i; float f; } v; v.i = ((unsigned int)u) << 16; return v.f;
}
__device__ __forceinline__ u16 f2b(float f) {
    union { float ff; unsigned int i; } v; v.ff = f;
    unsigned int x = v.i;
    unsigned int r = (x + 0x7fffu + ((x >> 16) & 1u)) >> 16;
    return (u16)r;
}

// ---------------- kcvt: xbT[b,l,d] = bf16(x^T) ----------------
// grid (64 ltiles, 6 dtiles, 16 b), block 256; 64x64 tile via LDS
__global__ __launch_bounds__(256) void kcvt(const float* __restrict__ x,
                                            u16* __restrict__ xbT) {
    __shared__ __align__(16) u16 T[64][72];
    const int t = threadIdx.x;
    const int l0 = blockIdx.x * 64;
    const int d0 = blockIdx.y * 64;
    const int b = blockIdx.z;
    const int dr = t >> 2;
    const int lo = (t & 3) * 16;
    const float* xp = x + ((size_t)(b * DMODEL + d0 + dr)) * LSEQ + l0 + lo;
    float4 x0 = *reinterpret_cast<const float4*>(xp + 0);
    float4 x1 = *reinterpret_cast<const float4*>(xp + 4);
    float4 x2 = *reinterpret_cast<const float4*>(xp + 8);
    float4 x3 = *reinterpret_cast<const float4*>(xp + 12);
    s16x8 va, vb;
    va[0] = (short)f2b(x0.x); va[1] = (short)f2b(x0.y); va[2] = (short)f2b(x0.z); va[3] = (short)f2b(x0.w);
    va[4] = (short)f2b(x1.x); va[5] = (short)f2b(x1.y); va[6] = (short)f2b(x1.z); va[7] = (short)f2b(x1.w);
    vb[0] = (short)f2b(x2.x); vb[1] = (short)f2b(x2.y); vb[2] = (short)f2b(x2.z); vb[3] = (short)f2b(x2.w);
    vb[4] = (short)f2b(x3.x); vb[5] = (short)f2b(x3.y); vb[6] = (short)f2b(x3.z); vb[7] = (short)f2b(x3.w);
    *reinterpret_cast<s16x8*>(&T[dr][lo + 0]) = va;
    *reinterpret_cast<s16x8*>(&T[dr][lo + 8]) = vb;
    __syncthreads();
    const int lr = t >> 2;
    const int dof = (t & 3) * 16;
    s16x8 wa, wb;
    #pragma unroll
    for (int j = 0; j < 8; ++j) {
        wa[j] = (short)T[dof + j][lr];
        wb[j] = (short)T[dof + 8 + j][lr];
    }
    u16* xtp = xbT + ((size_t)(b * LSEQ + l0 + lr)) * DMODEL + d0 + dof;
    *reinterpret_cast<s16x8*>(xtp + 0) = wa;
    *reinterpret_cast<s16x8*>(xtp + 8) = wb;
}

// ---------------- k1: bcdt = W_bcdt x (MFMA). o<128 -> bf16 rawbc, o>=128 -> f32 rawdt
// grid (16 ltiles of 256, 3 otiles of 64, 16 b), block 256 (4 waves, 2x2)
__global__ __launch_bounds__(256) void k1_mfma(const u16* __restrict__ xbT,
                                               const float* __restrict__ Wb,
                                               u16* __restrict__ rawbc,
                                               float* __restrict__ rawdt) {
    __shared__ __align__(16) short As[64 * 40];
    __shared__ __align__(16) short Bs[256 * 40];
    const int t = threadIdx.x;
    const int l0 = blockIdx.x * 256;
    const int o0 = blockIdx.y * 64;
    const int b = blockIdx.z;
    const int lane = t & 63;
    const int w = t >> 6;
    const int wm = w >> 1, wn = w & 1;
    const int lm = lane & 15, kg = lane >> 4;
    f32x4 acc[2][8];
    #pragma unroll
    for (int i = 0; i < 2; ++i)
        #pragma unroll
        for (int j = 0; j < 8; ++j) acc[i][j] = (f32x4){0.f, 0.f, 0.f, 0.f};

    const int arow = t >> 2;            // 0..63
    const int aoff = (t & 3) * 8;       // 0,8,16,24
    const float* wp = Wb + (size_t)(o0 + arow) * DMODEL + aoff;
    const u16* bp = xbT + ((size_t)(b * LSEQ + l0)) * DMODEL;

    for (int kc = 0; kc < DMODEL; kc += 32) {
        float4 w0 = *reinterpret_cast<const float4*>(wp + kc);
        float4 w1 = *reinterpret_cast<const float4*>(wp + kc + 4);
        s16x8 av;
        av[0] = (short)f2b(w0.x); av[1] = (short)f2b(w0.y); av[2] = (short)f2b(w0.z); av[3] = (short)f2b(w0.w);
        av[4] = (short)f2b(w1.x); av[5] = (short)f2b(w1.y); av[6] = (short)f2b(w1.z); av[7] = (short)f2b(w1.w);
        *reinterpret_cast<s16x8*>(&As[arow * 40 + aoff]) = av;
        #pragma unroll
        for (int i = 0; i < 4; ++i) {
            int c = t + i * 256;
            int brow = c >> 2;
            int boff = (c & 3) * 8;
            s16x8 bv = *reinterpret_cast<const s16x8*>(bp + (size_t)brow * DMODEL + kc + boff);
            *reinterpret_cast<s16x8*>(&Bs[brow * 40 + boff]) = bv;
        }
        __syncthreads();
        s16x8 af[2], bf[8];
        #pragma unroll
        for (int i = 0; i < 2; ++i)
            af[i] = *reinterpret_cast<s16x8*>(&As[(wm * 32 + i * 16 + lm) * 40 + kg * 8]);
        #pragma unroll
        for (int j = 0; j < 8; ++j)
            bf[j] = *reinterpret_cast<s16x8*>(&Bs[(wn * 128 + j * 16 + lm) * 40 + kg * 8]);
        #pragma unroll
        for (int i = 0; i < 2; ++i)
            #pragma unroll
            for (int j = 0; j < 8; ++j)
                acc[i][j] = __builtin_amdgcn_mfma_f32_16x16x32_bf16(af[i], bf[j], acc[i][j], 0, 0, 0);
        __syncthreads();
    }
    #pragma unroll
    for (int i = 0; i < 2; ++i) {
        #pragma unroll
        for (int j = 0; j < 8; ++j) {
            #pragma unroll
            for (int r = 0; r < 4; ++r) {
                int o = o0 + wm * 32 + i * 16 + kg * 4 + r;
                int l = l0 + wn * 128 + j * 16 + lm;
                float val = acc[i][j][r];
                if (o < 128) rawbc[((size_t)b * 128 + o) * LSEQ + l] = f2b(val);
                else         rawdt[((size_t)b * 64 + (o - 128)) * LSEQ + l] = val;
            }
        }
    }
}

// ---------------- k2c: Cm[b,s,l] = dwconv3x3(rawbc ch 64+s) (f32 out to ws) --------
// grid (16 rowgroups, 64 s, 16 b), block 256 = 4 rows x 64 cols
__global__ __launch_bounds__(256) void k2c_cm(const u16* __restrict__ rawbc,
                                              const float* __restrict__ Wdw,
                                              float* __restrict__ Cm) {
    const int t = threadIdx.x;
    const int rg = blockIdx.x;
    const int c = blockIdx.y;
    const int b = blockIdx.z;
    const int row = rg * 4 + (t >> 6);
    const int col = t & 63;
    float w[9];
    #pragma unroll
    for (int k = 0; k < 9; ++k) w[k] = Wdw[(64 + c) * 9 + k];
    const u16* ip = rawbc + ((size_t)b * 128 + 64 + c) * LSEQ;
    float acc = 0.f;
    #pragma unroll
    for (int dy = -1; dy <= 1; ++dy) {
        int r = row + dy;
        if (r < 0 || r > 63) continue;
        #pragma unroll
        for (int dx = -1; dx <= 1; ++dx) {
            int cc = col + dx;
            if (cc < 0 || cc > 63) continue;
            acc = fmaf(w[(dy + 1) * 3 + (dx + 1)], b2f(ip[r * 64 + cc]), acc);
        }
    }
    Cm[((size_t)b * SDIM + c) * LSEQ + row * 64 + col] = acc;
}

// ---------------- k23: fused dwconv(B,dt) + softmax + AB = A*Bconv (bf16 out) ------
// grid (64 s, 16 b), block 256, 16 pixels/thread
__global__ __launch_bounds__(256) void k23_ab(const u16* __restrict__ rawbc,
                                              const float* __restrict__ rawdt,
                                              const float* __restrict__ Wdw,
                                              const float* __restrict__ Ap,
                                              u16* __restrict__ AB) {
    __shared__ float chB[LSEQ];
    __shared__ float chT[LSEQ];
    __shared__ float red[4];
    const int t = threadIdx.x;
    const int s = blockIdx.x;
    const int b = blockIdx.y;
    const u16* rB = rawbc + ((size_t)b * 128 + s) * LSEQ;
    const float* rT = rawdt + ((size_t)b * 64 + s) * LSEQ;
    #pragma unroll
    for (int i = 0; i < 16; ++i) {
        int idx = t + i * 256;
        chB[idx] = b2f(rB[idx]);
        chT[idx] = rT[idx];
    }
    __syncthreads();
    float wB[9], wT[9];
    #pragma unroll
    for (int k = 0; k < 9; ++k) {
        wB[k] = Wdw[s * 9 + k];
        wT[k] = Wdw[(128 + s) * 9 + k];
    }
    const float a = Ap[s];
    float vB[16], vT[16];
    float m = -3.0e38f;
    #pragma unroll
    for (int i = 0; i < 16; ++i) {
        int idx = t + i * 256;
        int row = idx >> 6, col = idx & 63;
        float aB = 0.f, aT = 0.f;
        #pragma unroll
        for (int dy = -1; dy <= 1; ++dy) {
            int r = row + dy;
            if (r < 0 || r > 63) continue;
            #pragma unroll
            for (int dx = -1; dx <= 1; ++dx) {
                int cc = col + dx;
                if (cc < 0 || cc > 63) continue;
                int p = r * 64 + cc;
                int wi = (dy + 1) * 3 + (dx + 1);
                aB = fmaf(wB[wi], chB[p], aB);
                aT = fmaf(wT[wi], chT[p], aT);
            }
        }
        vB[i] = aB;
        vT[i] = aT + a;
        m = fmaxf(m, vT[i]);
    }
    #pragma unroll
    for (int off = 32; off; off >>= 1) m = fmaxf(m, __shfl_xor(m, off));
    if ((t & 63) == 0) red[t >> 6] = m;
    __syncthreads();
    m = fmaxf(fmaxf(red[0], red[1]), fmaxf(red[2], red[3]));
    __syncthreads();
    float sum = 0.f;
    #pragma unroll
    for (int i = 0; i < 16; ++i) {
        vT[i] = expf(vT[i] - m);
        sum += vT[i];
    }
    #pragma unroll
    for (int off = 32; off; off >>= 1) sum += __shfl_xor(sum, off);
    if ((t & 63) == 0) red[t >> 6] = sum;
    __syncthreads();
    sum = red[0] + red[1] + red[2] + red[3];
    const float inv = 1.0f / sum;
    u16* op = AB + ((size_t)b * SDIM + s) * LSEQ;
    #pragma unroll
    for (int i = 0; i < 16; ++i) {
        int idx = t + i * 256;
        op[idx] = f2b(vT[i] * inv * vB[i]);
    }
}

// ---------------- k4: hpart[kc] = x_chunk AB_chunk^T (MFMA, inline f32->bf16) ------
// grid (4 kchunks, 6 dtiles of 64, 16 b), block 256 (4 waves, 2x2); K-chunk 1024
__global__ __launch_bounds__(256) void k4_mfma(const float* __restrict__ x,
                                               const u16* __restrict__ ABu,
                                               float* __restrict__ hpart) {
    __shared__ __align__(16) short As[64 * 40];
    __shared__ __align__(16) short Bs[64 * 40];
    const int t = threadIdx.x;
    const int kc = blockIdx.x;
    const int d0 = blockIdx.y * 64;
    const int b = blockIdx.z;
    const int lane = t & 63;
    const int w = t >> 6;
    const int wm = w >> 1, wn = w & 1;
    const int lm = lane & 15, kg = lane >> 4;
    const int arow = t >> 2;
    const int aoff = (t & 3) * 8;
    const float* ap = x + ((size_t)(b * DMODEL + d0 + arow)) * LSEQ + kc * 1024 + aoff;
    const u16* bp = ABu + ((size_t)(b * SDIM + arow)) * LSEQ + kc * 1024 + aoff;
    f32x4 acc[2][2];
    #pragma unroll
    for (int i = 0; i < 2; ++i)
        #pragma unroll
        for (int j = 0; j < 2; ++j) acc[i][j] = (f32x4){0.f, 0.f, 0.f, 0.f};

    for (int ks = 0; ks < 1024; ks += 32) {
        float4 a0 = *reinterpret_cast<const float4*>(ap + ks);
        float4 a1 = *reinterpret_cast<const float4*>(ap + ks + 4);
        s16x8 av;
        av[0] = (short)f2b(a0.x); av[1] = (short)f2b(a0.y); av[2] = (short)f2b(a0.z); av[3] = (short)f2b(a0.w);
        av[4] = (short)f2b(a1.x); av[5] = (short)f2b(a1.y); av[6] = (short)f2b(a1.z); av[7] = (short)f2b(a1.w);
        s16x8 bv = *reinterpret_cast<const s16x8*>(bp + ks);
        *reinterpret_cast<s16x8*>(&As[arow * 40 + aoff]) = av;
        *reinterpret_cast<s16x8*>(&Bs[arow * 40 + aoff]) = bv;
        __syncthreads();
        s16x8 af[2], bf[2];
        #pragma unroll
        for (int i = 0; i < 2; ++i) {
            af[i] = *reinterpret_cast<s16x8*>(&As[(wm * 32 + i * 16 + lm) * 40 + kg * 8]);
            bf[i] = *reinterpret_cast<s16x8*>(&Bs[(wn * 32 + i * 16 + lm) * 40 + kg * 8]);
        }
        #pragma unroll
        for (int i = 0; i < 2; ++i)
            #pragma unroll
            for (int j = 0; j < 2; ++j)
                acc[i][j] = __builtin_amdgcn_mfma_f32_16x16x32_bf16(af[i], bf[j], acc[i][j], 0, 0, 0);
        __syncthreads();
    }
    #pragma unroll
    for (int i = 0; i < 2; ++i) {
        #pragma unroll
        for (int j = 0; j < 2; ++j) {
            #pragma unroll
            for (int r = 0; r < 4; ++r) {
                int d = d0 + wm * 32 + i * 16 + kg * 4 + r;
                int s = wn * 32 + j * 16 + lm;
                hpart[(size_t)kc * (NB * DMODEL * SDIM) + ((size_t)b * DMODEL + d) * SDIM + s] = acc[i][j][r];
            }
        }
    }
}

// ---------------- k4r: h = sum of 4 hparts ----------------
__global__ __launch_bounds__(256) void k4r(const float* __restrict__ hp,
                                           float* __restrict__ h) {
    const int i = blockIdx.x * 256 + threadIdx.x;   // grid 1536 covers 393216
    const int N = NB * DMODEL * SDIM;
    h[i] = hp[i] + hp[i + N] + hp[i + 2 * N] + hp[i + 3 * N];
}

// ---------------- k5a: hgate[b,o,s] = h1*silu(z) + h1*D ----------------
__global__ __launch_bounds__(256) void k5a(const float* __restrict__ h,
                                           const float* __restrict__ Whz,
                                           const float* __restrict__ Dp,
                                           float* __restrict__ hgate) {
    const int t = threadIdx.x;
    const int ot = blockIdx.x;
    const int b = blockIdx.y;
    const int s = t & 63;
    const int og = t >> 6;
    const int o0 = ot * 16 + og * 4;
    const float* hp = h + (size_t)b * DMODEL * SDIM + s;
    float acc1[4] = {0.f, 0.f, 0.f, 0.f};
    float acc2[4] = {0.f, 0.f, 0.f, 0.f};
    for (int d = 0; d < DMODEL; d += 2) {
        float h0 = hp[(size_t)d * SDIM];
        float h1 = hp[(size_t)(d + 1) * SDIM];
        #pragma unroll
        for (int k = 0; k < 4; ++k) {
            float2 w1 = *reinterpret_cast<const float2*>(&Whz[(o0 + k) * DMODEL + d]);
            float2 w2 = *reinterpret_cast<const float2*>(&Whz[(DMODEL + o0 + k) * DMODEL + d]);
            acc1[k] = fmaf(w1.x, h0, acc1[k]);
            acc1[k] = fmaf(w1.y, h1, acc1[k]);
            acc2[k] = fmaf(w2.x, h0, acc2[k]);
            acc2[k] = fmaf(w2.y, h1, acc2[k]);
        }
    }
    const float Dv = Dp[0];
    float* gp = hgate + ((size_t)b * DMODEL + o0) * SDIM + s;
    #pragma unroll
    for (int k = 0; k < 4; ++k) {
        float z = acc2[k];
        float sig = 1.f / (1.f + expf(-z));
        gp[(size_t)k * SDIM] = acc1[k] * (z * sig) + acc1[k] * Dv;
    }
}

// ---------------- k5b: hout[b,o,s] = W_out hgate (f32 to d_out tail) ----------------
__global__ __launch_bounds__(256) void k5b(const float* __restrict__ hg,
                                           const float* __restrict__ Wout,
                                           float* __restrict__ ho) {
    const int t = threadIdx.x;
    const int ot = blockIdx.x;
    const int b = blockIdx.y;
    const int s = t & 63;
    const int og = t >> 6;
    const int o0 = ot * 16 + og * 4;
    const float* gp = hg + (size_t)b * DMODEL * SDIM + s;
    float acc[4] = {0.f, 0.f, 0.f, 0.f};
    for (int d = 0; d < DMODEL; d += 2) {
        float g0 = gp[(size_t)d * SDIM];
        float g1 = gp[(size_t)(d + 1) * SDIM];
        #pragma unroll
        for (int k = 0; k < 4; ++k) {
            float2 w = *reinterpret_cast<const float2*>(&Wout[(o0 + k) * DMODEL + d]);
            acc[k] = fmaf(w.x, g0, acc[k]);
            acc[k] = fmaf(w.y, g1, acc[k]);
        }
    }
    float* op = ho + ((size_t)b * DMODEL + o0) * SDIM + s;
    #pragma unroll
    for (int k = 0; k < 4; ++k) op[(size_t)k * SDIM] = acc[k];
}

// ---------------- k6: y[b,d,l] = sum_s hout[b,d,s] * Cm[b,s,l] ----------------
// grid (16 ltiles, 24 dtiles of 16, 16 b), block 256 (one l each), 16 d per thread
__global__ __launch_bounds__(256) void k6_y(const float* __restrict__ Cm,
                                            const float* __restrict__ ho,
                                            float* __restrict__ y) {
    __shared__ float hs[16 * 64];
    const int t = threadIdx.x;
    const int lt = blockIdx.x;
    const int dtile = blockIdx.y;
    const int b = blockIdx.z;
    const int l = lt * 256 + t;
    const int d0 = dtile * 16;
    #pragma unroll
    for (int i = 0; i < 4; ++i) {
        int idx = t + i * 256;
        int k = idx >> 6, s = idx & 63;
        hs[idx] = ho[((size_t)b * DMODEL + d0 + k) * SDIM + s];
    }
    __syncthreads();
    const float* cp = Cm + (size_t)b * SDIM * LSEQ + l;
    float acc[16];
    #pragma unroll
    for (int k = 0; k < 16; ++k) acc[k] = 0.f;
    for (int s = 0; s < SDIM; ++s) {
        float cv = cp[(size_t)s * LSEQ];
        #pragma unroll
        for (int k = 0; k < 16; ++k) acc[k] = fmaf(hs[k * 64 + s], cv, acc[k]);
    }
    float* yp = y + ((size_t)b * DMODEL + d0) * LSEQ + l;
    #pragma unroll
    for (int k = 0; k < 16; ++k) yp[(size_t)k * LSEQ] = acc[k];
}

extern "C" void kernel_launch(void* const* d_in, const int* in_sizes, int n_in,
                              void* d_out, int out_size, void* d_ws, size_t ws_size,
                              hipStream_t stream) {
    const float* x    = (const float*)d_in[0];
    const float* Wb   = (const float*)d_in[1];
    const float* Wdw  = (const float*)d_in[2];
    const float* Whz  = (const float*)d_in[3];
    const float* Wout = (const float*)d_in[4];
    const float* Ap   = (const float*)d_in[5];
    const float* Dp   = (const float*)d_in[6];

    float* out = (float*)d_out;
    const size_t YSIZE = (size_t)NB * DMODEL * LSEQ;   // 25165824 floats

    // d_out y-region scratch map (float offsets). All dead before k6 rewrites y.
    //   RAWBC (u16) [0,        4194304)   bcdt ch 0..127 (B,C) bf16   (8.39M u16)
    //   RAWDT (f32) [4194304,  8388608)   bcdt ch 128..191 (dt) f32   (4.19M f32)
    //   XBT   (u16) [8388608,  20971520)  bf16 x^T [b,l,d]            (25.17M u16)
    //   AB    (u16) [20971520, 23068672)  bf16 AB [b,s,l]             (4.19M u16)
    //   After k23, RAWBC/RAWDT dead -> reuse RAWBC region:
    //   HPART (f32) [0, 1572864), H [1572864, 1966080), HG [1966080, 2359296)
    u16*   RAWBC = (u16*)out;
    float* RAWDT = out + 4194304;
    u16*   XBT   = (u16*)(out + 8388608);
    u16*   ABu   = (u16*)(out + 20971520);
    float* HPART = out;
    float* H     = out + 1572864;
    float* HG    = out + 1966080;
    float* HO    = out + YSIZE;        // hout output (f32)
    float* Cm    = (float*)d_ws;       // 16.8 MB (k6 reads while y is written)

    kcvt   <<<dim3(64, 6, NB), 256, 0, stream>>>(x, XBT);
    k1_mfma<<<dim3(16, 3, NB), 256, 0, stream>>>(XBT, Wb, RAWBC, RAWDT);
    k2c_cm <<<dim3(16, SDIM, NB), 256, 0, stream>>>(RAWBC, Wdw, Cm);
    k23_ab <<<dim3(SDIM, NB), 256, 0, stream>>>(RAWBC, RAWDT, Wdw, Ap, ABu);
    k4_mfma<<<dim3(4, 6, NB), 256, 0, stream>>>(x, ABu, HPART);
    k4r    <<<dim3(1536), 256, 0, stream>>>(HPART, H);
    k5a    <<<dim3(24, NB), 256, 0, stream>>>(H, Whz, Dp, HG);
    k5b    <<<dim3(24, NB), 256, 0, stream>>>(HG, Wout, HO);
    k6_y   <<<dim3(16, 24, NB), 256, 0, stream>>>(Cm, HO, out);
}

// Round 6
// 239.014 us; speedup vs baseline: 2.0510x; 1.1516x over previous
//
#include <hip/hip_runtime.h>

typedef unsigned short u16;
typedef short s16x8 __attribute__((ext_vector_type(8)));
typedef float f32x4 __attribute__((ext_vector_type(4)));

#define NB 16
#define DMODEL 384
#define SDIM 64
#define LSEQ 4096
#define C3S 192

__device__ __forceinline__ float b2f(u16 u) {
    union { unsigned int i; float f; } v; v.i = ((unsigned int)u) << 16; return v.f;
}
__device__ __forceinline__ u16 f2b(float f) {
    union { float ff; unsigned int i; } v; v.ff = f;
    unsigned int x = v.i;
    unsigned int r = (x + 0x7fffu + ((x >> 16) & 1u)) >> 16;
    return (u16)r;
}

// ---------------- kcvt: xbT[b,l,d] = bf16(x^T) ----------------
// grid (64 ltiles, 6 dtiles, 16 b), block 256; 64x64 tile via LDS
__global__ __launch_bounds__(256) void kcvt(const float* __restrict__ x,
                                            u16* __restrict__ xbT) {
    __shared__ __align__(16) u16 T[64][72];
    const int t = threadIdx.x;
    const int l0 = blockIdx.x * 64;
    const int d0 = blockIdx.y * 64;
    const int b = blockIdx.z;
    const int dr = t >> 2;
    const int lo = (t & 3) * 16;
    const float* xp = x + ((size_t)(b * DMODEL + d0 + dr)) * LSEQ + l0 + lo;
    float4 x0 = *reinterpret_cast<const float4*>(xp + 0);
    float4 x1 = *reinterpret_cast<const float4*>(xp + 4);
    float4 x2 = *reinterpret_cast<const float4*>(xp + 8);
    float4 x3 = *reinterpret_cast<const float4*>(xp + 12);
    s16x8 va, vb;
    va[0] = (short)f2b(x0.x); va[1] = (short)f2b(x0.y); va[2] = (short)f2b(x0.z); va[3] = (short)f2b(x0.w);
    va[4] = (short)f2b(x1.x); va[5] = (short)f2b(x1.y); va[6] = (short)f2b(x1.z); va[7] = (short)f2b(x1.w);
    vb[0] = (short)f2b(x2.x); vb[1] = (short)f2b(x2.y); vb[2] = (short)f2b(x2.z); vb[3] = (short)f2b(x2.w);
    vb[4] = (short)f2b(x3.x); vb[5] = (short)f2b(x3.y); vb[6] = (short)f2b(x3.z); vb[7] = (short)f2b(x3.w);
    *reinterpret_cast<s16x8*>(&T[dr][lo + 0]) = va;
    *reinterpret_cast<s16x8*>(&T[dr][lo + 8]) = vb;
    __syncthreads();
    const int lr = t >> 2;
    const int dof = (t & 3) * 16;
    s16x8 wa, wb;
    #pragma unroll
    for (int j = 0; j < 8; ++j) {
        wa[j] = (short)T[dof + j][lr];
        wb[j] = (short)T[dof + 8 + j][lr];
    }
    u16* xtp = xbT + ((size_t)(b * LSEQ + l0 + lr)) * DMODEL + d0 + dof;
    *reinterpret_cast<s16x8*>(xtp + 0) = wa;
    *reinterpret_cast<s16x8*>(xtp + 8) = wb;
}

// ---------------- k1: bcdt = W_bcdt x (MFMA). o<128 -> bf16 rawbc, o>=128 -> f32 rawdt
// grid (16 ltiles of 256, 3 otiles of 64, 16 b), block 256 (4 waves, 2x2)
__global__ __launch_bounds__(256) void k1_mfma(const u16* __restrict__ xbT,
                                               const float* __restrict__ Wb,
                                               u16* __restrict__ rawbc,
                                               float* __restrict__ rawdt) {
    __shared__ __align__(16) short As[64 * 40];
    __shared__ __align__(16) short Bs[256 * 40];
    const int t = threadIdx.x;
    const int l0 = blockIdx.x * 256;
    const int o0 = blockIdx.y * 64;
    const int b = blockIdx.z;
    const int lane = t & 63;
    const int w = t >> 6;
    const int wm = w >> 1, wn = w & 1;
    const int lm = lane & 15, kg = lane >> 4;
    f32x4 acc[2][8];
    #pragma unroll
    for (int i = 0; i < 2; ++i)
        #pragma unroll
        for (int j = 0; j < 8; ++j) acc[i][j] = (f32x4){0.f, 0.f, 0.f, 0.f};

    const int arow = t >> 2;            // 0..63
    const int aoff = (t & 3) * 8;       // 0,8,16,24
    const float* wp = Wb + (size_t)(o0 + arow) * DMODEL + aoff;
    const u16* bp = xbT + ((size_t)(b * LSEQ + l0)) * DMODEL;

    for (int kc = 0; kc < DMODEL; kc += 32) {
        float4 w0 = *reinterpret_cast<const float4*>(wp + kc);
        float4 w1 = *reinterpret_cast<const float4*>(wp + kc + 4);
        s16x8 av;
        av[0] = (short)f2b(w0.x); av[1] = (short)f2b(w0.y); av[2] = (short)f2b(w0.z); av[3] = (short)f2b(w0.w);
        av[4] = (short)f2b(w1.x); av[5] = (short)f2b(w1.y); av[6] = (short)f2b(w1.z); av[7] = (short)f2b(w1.w);
        *reinterpret_cast<s16x8*>(&As[arow * 40 + aoff]) = av;
        #pragma unroll
        for (int i = 0; i < 4; ++i) {
            int c = t + i * 256;
            int brow = c >> 2;
            int boff = (c & 3) * 8;
            s16x8 bv = *reinterpret_cast<const s16x8*>(bp + (size_t)brow * DMODEL + kc + boff);
            *reinterpret_cast<s16x8*>(&Bs[brow * 40 + boff]) = bv;
        }
        __syncthreads();
        s16x8 af[2], bf[8];
        #pragma unroll
        for (int i = 0; i < 2; ++i)
            af[i] = *reinterpret_cast<s16x8*>(&As[(wm * 32 + i * 16 + lm) * 40 + kg * 8]);
        #pragma unroll
        for (int j = 0; j < 8; ++j)
            bf[j] = *reinterpret_cast<s16x8*>(&Bs[(wn * 128 + j * 16 + lm) * 40 + kg * 8]);
        #pragma unroll
        for (int i = 0; i < 2; ++i)
            #pragma unroll
            for (int j = 0; j < 8; ++j)
                acc[i][j] = __builtin_amdgcn_mfma_f32_16x16x32_bf16(af[i], bf[j], acc[i][j], 0, 0, 0);
        __syncthreads();
    }
    #pragma unroll
    for (int i = 0; i < 2; ++i) {
        #pragma unroll
        for (int j = 0; j < 8; ++j) {
            #pragma unroll
            for (int r = 0; r < 4; ++r) {
                int o = o0 + wm * 32 + i * 16 + kg * 4 + r;
                int l = l0 + wn * 128 + j * 16 + lm;
                float val = acc[i][j][r];
                if (o < 128) rawbc[((size_t)b * 128 + o) * LSEQ + l] = f2b(val);
                else         rawdt[((size_t)b * 64 + (o - 128)) * LSEQ + l] = val;
            }
        }
    }
}

// ---------------- k2c: CMB[b,s,l] = bf16(dwconv3x3(rawbc ch 64+s)) ----------------
// grid (16 rowgroups, 64 s, 16 b), block 256 = 4 rows x 64 cols
__global__ __launch_bounds__(256) void k2c_cm(const u16* __restrict__ rawbc,
                                              const float* __restrict__ Wdw,
                                              u16* __restrict__ CMB) {
    const int t = threadIdx.x;
    const int rg = blockIdx.x;
    const int c = blockIdx.y;
    const int b = blockIdx.z;
    const int row = rg * 4 + (t >> 6);
    const int col = t & 63;
    float w[9];
    #pragma unroll
    for (int k = 0; k < 9; ++k) w[k] = Wdw[(64 + c) * 9 + k];
    const u16* ip = rawbc + ((size_t)b * 128 + 64 + c) * LSEQ;
    float acc = 0.f;
    #pragma unroll
    for (int dy = -1; dy <= 1; ++dy) {
        int r = row + dy;
        if (r < 0 || r > 63) continue;
        #pragma unroll
        for (int dx = -1; dx <= 1; ++dx) {
            int cc = col + dx;
            if (cc < 0 || cc > 63) continue;
            acc = fmaf(w[(dy + 1) * 3 + (dx + 1)], b2f(ip[r * 64 + cc]), acc);
        }
    }
    CMB[((size_t)b * SDIM + c) * LSEQ + row * 64 + col] = f2b(acc);
}

// ---------------- kcmT: CmT[b,l,s] = CMB[b,s,l]^T (bf16, LDS transpose) ----------
// grid (64 ltiles, 16 b), block 256
__global__ __launch_bounds__(256) void kcmT(const u16* __restrict__ CMB,
                                            u16* __restrict__ CmT) {
    __shared__ __align__(16) u16 T[64][72];
    const int t = threadIdx.x;
    const int l0 = blockIdx.x * 64;
    const int b = blockIdx.y;
    const int sr = t >> 2;
    const int lo = (t & 3) * 16;
    const u16* ip = CMB + ((size_t)(b * SDIM + sr)) * LSEQ + l0 + lo;
    s16x8 va = *reinterpret_cast<const s16x8*>(ip);
    s16x8 vb = *reinterpret_cast<const s16x8*>(ip + 8);
    *reinterpret_cast<s16x8*>(&T[sr][lo + 0]) = va;
    *reinterpret_cast<s16x8*>(&T[sr][lo + 8]) = vb;
    __syncthreads();
    const int lr = t >> 2;
    const int sof = (t & 3) * 16;
    s16x8 wa, wb;
    #pragma unroll
    for (int j = 0; j < 8; ++j) {
        wa[j] = (short)T[sof + j][lr];
        wb[j] = (short)T[sof + 8 + j][lr];
    }
    u16* op = CmT + ((size_t)(b * LSEQ + l0 + lr)) * SDIM + sof;
    *reinterpret_cast<s16x8*>(op + 0) = wa;
    *reinterpret_cast<s16x8*>(op + 8) = wb;
}

// ---------------- k23: fused dwconv(B,dt) + softmax + AB = A*Bconv (bf16 out) ------
// grid (64 s, 16 b), block 256, 16 pixels/thread
__global__ __launch_bounds__(256) void k23_ab(const u16* __restrict__ rawbc,
                                              const float* __restrict__ rawdt,
                                              const float* __restrict__ Wdw,
                                              const float* __restrict__ Ap,
                                              u16* __restrict__ AB) {
    __shared__ float chB[LSEQ];
    __shared__ float chT[LSEQ];
    __shared__ float red[4];
    const int t = threadIdx.x;
    const int s = blockIdx.x;
    const int b = blockIdx.y;
    const u16* rB = rawbc + ((size_t)b * 128 + s) * LSEQ;
    const float* rT = rawdt + ((size_t)b * 64 + s) * LSEQ;
    #pragma unroll
    for (int i = 0; i < 16; ++i) {
        int idx = t + i * 256;
        chB[idx] = b2f(rB[idx]);
        chT[idx] = rT[idx];
    }
    __syncthreads();
    float wB[9], wT[9];
    #pragma unroll
    for (int k = 0; k < 9; ++k) {
        wB[k] = Wdw[s * 9 + k];
        wT[k] = Wdw[(128 + s) * 9 + k];
    }
    const float a = Ap[s];
    float vB[16], vT[16];
    float m = -3.0e38f;
    #pragma unroll
    for (int i = 0; i < 16; ++i) {
        int idx = t + i * 256;
        int row = idx >> 6, col = idx & 63;
        float aB = 0.f, aT = 0.f;
        #pragma unroll
        for (int dy = -1; dy <= 1; ++dy) {
            int r = row + dy;
            if (r < 0 || r > 63) continue;
            #pragma unroll
            for (int dx = -1; dx <= 1; ++dx) {
                int cc = col + dx;
                if (cc < 0 || cc > 63) continue;
                int p = r * 64 + cc;
                int wi = (dy + 1) * 3 + (dx + 1);
                aB = fmaf(wB[wi], chB[p], aB);
                aT = fmaf(wT[wi], chT[p], aT);
            }
        }
        vB[i] = aB;
        vT[i] = aT + a;
        m = fmaxf(m, vT[i]);
    }
    #pragma unroll
    for (int off = 32; off; off >>= 1) m = fmaxf(m, __shfl_xor(m, off));
    if ((t & 63) == 0) red[t >> 6] = m;
    __syncthreads();
    m = fmaxf(fmaxf(red[0], red[1]), fmaxf(red[2], red[3]));
    __syncthreads();
    float sum = 0.f;
    #pragma unroll
    for (int i = 0; i < 16; ++i) {
        vT[i] = expf(vT[i] - m);
        sum += vT[i];
    }
    #pragma unroll
    for (int off = 32; off; off >>= 1) sum += __shfl_xor(sum, off);
    if ((t & 63) == 0) red[t >> 6] = sum;
    __syncthreads();
    sum = red[0] + red[1] + red[2] + red[3];
    const float inv = 1.0f / sum;
    u16* op = AB + ((size_t)b * SDIM + s) * LSEQ;
    #pragma unroll
    for (int i = 0; i < 16; ++i) {
        int idx = t + i * 256;
        op[idx] = f2b(vT[i] * inv * vB[i]);
    }
}

// ---------------- k4: hpart[kc] = x_chunk AB_chunk^T (MFMA, inline f32->bf16) ------
// grid (4 kchunks, 6 dtiles of 64, 16 b), block 256 (4 waves, 2x2); K-chunk 1024
__global__ __launch_bounds__(256) void k4_mfma(const float* __restrict__ x,
                                               const u16* __restrict__ ABu,
                                               float* __restrict__ hpart) {
    __shared__ __align__(16) short As[64 * 40];
    __shared__ __align__(16) short Bs[64 * 40];
    const int t = threadIdx.x;
    const int kc = blockIdx.x;
    const int d0 = blockIdx.y * 64;
    const int b = blockIdx.z;
    const int lane = t & 63;
    const int w = t >> 6;
    const int wm = w >> 1, wn = w & 1;
    const int lm = lane & 15, kg = lane >> 4;
    const int arow = t >> 2;
    const int aoff = (t & 3) * 8;
    const float* ap = x + ((size_t)(b * DMODEL + d0 + arow)) * LSEQ + kc * 1024 + aoff;
    const u16* bp = ABu + ((size_t)(b * SDIM + arow)) * LSEQ + kc * 1024 + aoff;
    f32x4 acc[2][2];
    #pragma unroll
    for (int i = 0; i < 2; ++i)
        #pragma unroll
        for (int j = 0; j < 2; ++j) acc[i][j] = (f32x4){0.f, 0.f, 0.f, 0.f};

    for (int ks = 0; ks < 1024; ks += 32) {
        float4 a0 = *reinterpret_cast<const float4*>(ap + ks);
        float4 a1 = *reinterpret_cast<const float4*>(ap + ks + 4);
        s16x8 av;
        av[0] = (short)f2b(a0.x); av[1] = (short)f2b(a0.y); av[2] = (short)f2b(a0.z); av[3] = (short)f2b(a0.w);
        av[4] = (short)f2b(a1.x); av[5] = (short)f2b(a1.y); av[6] = (short)f2b(a1.z); av[7] = (short)f2b(a1.w);
        s16x8 bv = *reinterpret_cast<const s16x8*>(bp + ks);
        *reinterpret_cast<s16x8*>(&As[arow * 40 + aoff]) = av;
        *reinterpret_cast<s16x8*>(&Bs[arow * 40 + aoff]) = bv;
        __syncthreads();
        s16x8 af[2], bf[2];
        #pragma unroll
        for (int i = 0; i < 2; ++i) {
            af[i] = *reinterpret_cast<s16x8*>(&As[(wm * 32 + i * 16 + lm) * 40 + kg * 8]);
            bf[i] = *reinterpret_cast<s16x8*>(&Bs[(wn * 32 + i * 16 + lm) * 40 + kg * 8]);
        }
        #pragma unroll
        for (int i = 0; i < 2; ++i)
            #pragma unroll
            for (int j = 0; j < 2; ++j)
                acc[i][j] = __builtin_amdgcn_mfma_f32_16x16x32_bf16(af[i], bf[j], acc[i][j], 0, 0, 0);
        __syncthreads();
    }
    #pragma unroll
    for (int i = 0; i < 2; ++i) {
        #pragma unroll
        for (int j = 0; j < 2; ++j) {
            #pragma unroll
            for (int r = 0; r < 4; ++r) {
                int d = d0 + wm * 32 + i * 16 + kg * 4 + r;
                int s = wn * 32 + j * 16 + lm;
                hpart[(size_t)kc * (NB * DMODEL * SDIM) + ((size_t)b * DMODEL + d) * SDIM + s] = acc[i][j][r];
            }
        }
    }
}

// ---------------- k4r: h = sum of 4 hparts ----------------
__global__ __launch_bounds__(256) void k4r(const float* __restrict__ hp,
                                           float* __restrict__ h) {
    const int i = blockIdx.x * 256 + threadIdx.x;   // grid 1536 covers 393216
    const int N = NB * DMODEL * SDIM;
    h[i] = hp[i] + hp[i + N] + hp[i + 2 * N] + hp[i + 3 * N];
}

// ---------------- k5a: hgate[b,o,s] = h1*silu(z) + h1*D ----------------
__global__ __launch_bounds__(256) void k5a(const float* __restrict__ h,
                                           const float* __restrict__ Whz,
                                           const float* __restrict__ Dp,
                                           float* __restrict__ hgate) {
    const int t = threadIdx.x;
    const int ot = blockIdx.x;
    const int b = blockIdx.y;
    const int s = t & 63;
    const int og = t >> 6;
    const int o0 = ot * 16 + og * 4;
    const float* hp = h + (size_t)b * DMODEL * SDIM + s;
    float acc1[4] = {0.f, 0.f, 0.f, 0.f};
    float acc2[4] = {0.f, 0.f, 0.f, 0.f};
    for (int d = 0; d < DMODEL; d += 2) {
        float h0 = hp[(size_t)d * SDIM];
        float h1 = hp[(size_t)(d + 1) * SDIM];
        #pragma unroll
        for (int k = 0; k < 4; ++k) {
            float2 w1 = *reinterpret_cast<const float2*>(&Whz[(o0 + k) * DMODEL + d]);
            float2 w2 = *reinterpret_cast<const float2*>(&Whz[(DMODEL + o0 + k) * DMODEL + d]);
            acc1[k] = fmaf(w1.x, h0, acc1[k]);
            acc1[k] = fmaf(w1.y, h1, acc1[k]);
            acc2[k] = fmaf(w2.x, h0, acc2[k]);
            acc2[k] = fmaf(w2.y, h1, acc2[k]);
        }
    }
    const float Dv = Dp[0];
    float* gp = hgate + ((size_t)b * DMODEL + o0) * SDIM + s;
    #pragma unroll
    for (int k = 0; k < 4; ++k) {
        float z = acc2[k];
        float sig = 1.f / (1.f + expf(-z));
        gp[(size_t)k * SDIM] = acc1[k] * (z * sig) + acc1[k] * Dv;
    }
}

// ---------------- k5b: hout f32 (output) + bf16 copy for k6 ----------------
__global__ __launch_bounds__(256) void k5b(const float* __restrict__ hg,
                                           const float* __restrict__ Wout,
                                           float* __restrict__ ho,
                                           u16* __restrict__ hob) {
    const int t = threadIdx.x;
    const int ot = blockIdx.x;
    const int b = blockIdx.y;
    const int s = t & 63;
    const int og = t >> 6;
    const int o0 = ot * 16 + og * 4;
    const float* gp = hg + (size_t)b * DMODEL * SDIM + s;
    float acc[4] = {0.f, 0.f, 0.f, 0.f};
    for (int d = 0; d < DMODEL; d += 2) {
        float g0 = gp[(size_t)d * SDIM];
        float g1 = gp[(size_t)(d + 1) * SDIM];
        #pragma unroll
        for (int k = 0; k < 4; ++k) {
            float2 w = *reinterpret_cast<const float2*>(&Wout[(o0 + k) * DMODEL + d]);
            acc[k] = fmaf(w.x, g0, acc[k]);
            acc[k] = fmaf(w.y, g1, acc[k]);
        }
    }
    float* op = ho + ((size_t)b * DMODEL + o0) * SDIM + s;
    u16* op2 = hob + ((size_t)b * DMODEL + o0) * SDIM + s;
    #pragma unroll
    for (int k = 0; k < 4; ++k) {
        op[(size_t)k * SDIM] = acc[k];
        op2[(size_t)k * SDIM] = f2b(acc[k]);
    }
}

// ---------------- k6: y[b,d,l] = sum_s hob[b,d,s] * CmT[b,l,s] (MFMA, no LDS) ------
// grid (32 ltiles of 128, 3 dtiles of 128, 16 b), block 256 (4 waves, 2x2)
__global__ __launch_bounds__(256) void k6_mfma(const u16* __restrict__ CmT,
                                               const u16* __restrict__ hob,
                                               float* __restrict__ y) {
    const int t = threadIdx.x;
    const int l0 = blockIdx.x * 128;
    const int d0 = blockIdx.y * 128;
    const int b = blockIdx.z;
    const int lane = t & 63;
    const int w = t >> 6;
    const int wm = w >> 1, wn = w & 1;
    const int lm = lane & 15, kg = lane >> 4;
    const u16* hp = hob + (size_t)b * DMODEL * SDIM;
    const u16* cp = CmT + (size_t)b * LSEQ * SDIM;
    s16x8 af[4][2], bf[4][2];
    #pragma unroll
    for (int i = 0; i < 4; ++i)
        #pragma unroll
        for (int ks = 0; ks < 2; ++ks)
            af[i][ks] = *reinterpret_cast<const s16x8*>(
                hp + (size_t)(d0 + wm * 64 + i * 16 + lm) * SDIM + ks * 32 + kg * 8);
    #pragma unroll
    for (int j = 0; j < 4; ++j)
        #pragma unroll
        for (int ks = 0; ks < 2; ++ks)
            bf[j][ks] = *reinterpret_cast<const s16x8*>(
                cp + (size_t)(l0 + wn * 64 + j * 16 + lm) * SDIM + ks * 32 + kg * 8);
    f32x4 acc[4][4];
    #pragma unroll
    for (int i = 0; i < 4; ++i)
        #pragma unroll
        for (int j = 0; j < 4; ++j) acc[i][j] = (f32x4){0.f, 0.f, 0.f, 0.f};
    #pragma unroll
    for (int ks = 0; ks < 2; ++ks)
        #pragma unroll
        for (int i = 0; i < 4; ++i)
            #pragma unroll
            for (int j = 0; j < 4; ++j)
                acc[i][j] = __builtin_amdgcn_mfma_f32_16x16x32_bf16(af[i][ks], bf[j][ks], acc[i][j], 0, 0, 0);
    float* yp = y + (size_t)b * DMODEL * LSEQ;
    #pragma unroll
    for (int i = 0; i < 4; ++i) {
        #pragma unroll
        for (int j = 0; j < 4; ++j) {
            #pragma unroll
            for (int r = 0; r < 4; ++r) {
                int d = d0 + wm * 64 + i * 16 + kg * 4 + r;
                int l = l0 + wn * 64 + j * 16 + lm;
                yp[(size_t)d * LSEQ + l] = acc[i][j][r];
            }
        }
    }
}

extern "C" void kernel_launch(void* const* d_in, const int* in_sizes, int n_in,
                              void* d_out, int out_size, void* d_ws, size_t ws_size,
                              hipStream_t stream) {
    const float* x    = (const float*)d_in[0];
    const float* Wb   = (const float*)d_in[1];
    const float* Wdw  = (const float*)d_in[2];
    const float* Whz  = (const float*)d_in[3];
    const float* Wout = (const float*)d_in[4];
    const float* Ap   = (const float*)d_in[5];
    const float* Dp   = (const float*)d_in[6];

    float* out = (float*)d_out;
    const size_t YSIZE = (size_t)NB * DMODEL * LSEQ;   // 25165824 floats

    // d_out y-region scratch (float offsets), all dead before k6 rewrites y:
    //   RAWBC (u16) [0,        4194304)   bcdt ch 0..127 bf16
    //   RAWDT (f32) [4194304,  8388608)   bcdt ch 128..191 f32 (dt)
    //   XBT   (u16) [8388608,  20971520)  bf16 x^T [b,l,d]  (dead after k1)
    //     CMB (u16) [8388608, 10485760)   bf16 Cm [b,s,l]   (written by k2c, after k1)
    //   AB    (u16) [20971520, 23068672)  bf16 AB [b,s,l]
    //   HPART (f32) [0, 1572864), H [1572864, 1966080), HG [1966080, 2359296)
    //     (reuse RAWBC region after k23)
    // ws: CmT (u16) [0, 4194304), HOB (u16) [4194304, 4587520)
    u16*   RAWBC = (u16*)out;
    float* RAWDT = out + 4194304;
    u16*   XBT   = (u16*)(out + 8388608);
    u16*   CMB   = (u16*)(out + 8388608);
    u16*   ABu   = (u16*)(out + 20971520);
    float* HPART = out;
    float* H     = out + 1572864;
    float* HG    = out + 1966080;
    float* HO    = out + YSIZE;        // hout output (f32)
    u16*   CmT   = (u16*)d_ws;
    u16*   HOB   = (u16*)d_ws + 4194304;

    kcvt   <<<dim3(64, 6, NB), 256, 0, stream>>>(x, XBT);
    k1_mfma<<<dim3(16, 3, NB), 256, 0, stream>>>(XBT, Wb, RAWBC, RAWDT);
    k2c_cm <<<dim3(16, SDIM, NB), 256, 0, stream>>>(RAWBC, Wdw, CMB);
    kcmT   <<<dim3(64, NB), 256, 0, stream>>>(CMB, CmT);
    k23_ab <<<dim3(SDIM, NB), 256, 0, stream>>>(RAWBC, RAWDT, Wdw, Ap, ABu);
    k4_mfma<<<dim3(4, 6, NB), 256, 0, stream>>>(x, ABu, HPART);
    k4r    <<<dim3(1536), 256, 0, stream>>>(HPART, H);
    k5a    <<<dim3(24, NB), 256, 0, stream>>>(H, Whz, Dp, HG);
    k5b    <<<dim3(24, NB), 256, 0, stream>>>(HG, Wout, HO, HOB);
    k6_mfma<<<dim3(32, 3, NB), 256, 0, stream>>>(CmT, HOB, out);
}